// Round 2
// baseline (2575.999 us; speedup 1.0000x reference)
//
#include <hip/hip_runtime.h>
#include <hip/hip_bf16.h>

typedef __bf16 bf16x8 __attribute__((ext_vector_type(8)));
typedef __bf16 bf16x4 __attribute__((ext_vector_type(4)));
typedef float floatx4 __attribute__((ext_vector_type(4)));

#define BM 128
#define BN 128
#define LFULL 4096

// C[Mc,N] = A[Mc,K](bf16) @ B[N,K](fp32->bf16)^T + bias(fp32)
//   RD=0: C -> bf16 compact chunk buffer
//   RD=1: C -> bf16 compact, R = fp32 global (token-slabbed rows)
//   RD=2: C -> fp32 global (token-slabbed rows), R = bf16 compact
// Compact chunk row m maps to global row: (m>>sT)*LFULL + t0 + (m & (T-1)).
template <int RD>
__global__ __launch_bounds__(256) void gemm_bt(
    const __bf16* __restrict__ A, const float* __restrict__ Bw,
    const float* __restrict__ bias, const void* __restrict__ Rp,
    void* __restrict__ Cp, int K, int N, int sT, int t0)
{
    __shared__ __align__(16) __bf16 As[4][BM][8];
    __shared__ __align__(16) __bf16 Bs[4][BN][8];

    const int tid  = threadIdx.x;
    const int m0   = blockIdx.y * BM;
    const int n0   = blockIdx.x * BN;
    const int wave = tid >> 6;
    const int lane = tid & 63;
    const int wm   = (wave & 1) * 64;
    const int wn   = (wave >> 1) * 64;

    // A staging: bf16, 16B per load
    const int lr = tid >> 2;   // 0..63
    const int lg = tid & 3;    // k-group 0..3
    // B staging: fp32 -> bf16, float4 per load
    const int brow = tid >> 3;        // 0..31
    const int bk   = (tid & 7) * 4;   // 0,4,..,28

    floatx4 acc[4][4] = {};

    const int q  = lane >> 4;
    const int ml = lane & 15;

    for (int k0 = 0; k0 < K; k0 += 32) {
        const __bf16* ap = A + (size_t)(m0 + lr) * K + k0 + lg * 8;
        bf16x8 a0 = *(const bf16x8*)ap;
        bf16x8 a1 = *(const bf16x8*)(ap + (size_t)64 * K);
        *(bf16x8*)&As[lg][lr][0]      = a0;
        *(bf16x8*)&As[lg][lr + 64][0] = a1;
#pragma unroll
        for (int rep = 0; rep < 4; rep++) {
            const int r = brow + rep * 32;
            float4 f = *(const float4*)(Bw + (size_t)(n0 + r) * K + k0 + bk);
            bf16x4 hv;
            hv[0] = (__bf16)f.x; hv[1] = (__bf16)f.y;
            hv[2] = (__bf16)f.z; hv[3] = (__bf16)f.w;
            *(bf16x4*)&Bs[bk >> 3][r][bk & 7] = hv;
        }
        __syncthreads();

        bf16x8 af[4], bfr[4];
#pragma unroll
        for (int i = 0; i < 4; i++) {
            af[i]  = *(const bf16x8*)&As[q][wm + i * 16 + ml][0];
            bfr[i] = *(const bf16x8*)&Bs[q][wn + i * 16 + ml][0];
        }
#pragma unroll
        for (int i = 0; i < 4; i++)
#pragma unroll
            for (int j = 0; j < 4; j++)
                acc[i][j] = __builtin_amdgcn_mfma_f32_16x16x32_bf16(af[i], bfr[j], acc[i][j], 0, 0, 0);
        __syncthreads();
    }

    const int Tmask = (1 << sT) - 1;
#pragma unroll
    for (int i = 0; i < 4; i++) {
#pragma unroll
        for (int j = 0; j < 4; j++) {
            const int n = n0 + wn + j * 16 + ml;
            const float bv = bias[n];
#pragma unroll
            for (int r = 0; r < 4; r++) {
                const int m = m0 + wm + i * 16 + q * 4 + r;
                float v = acc[i][j][r] + bv;
                if (RD == 1) {
                    const int gm = ((m >> sT) * LFULL) + t0 + (m & Tmask);
                    v += ((const float*)Rp)[(size_t)gm * N + n];
                    ((__bf16*)Cp)[(size_t)m * N + n] = (__bf16)v;
                } else if (RD == 2) {
                    v += (float)((const __bf16*)Rp)[(size_t)m * N + n];
                    const int gm = ((m >> sT) * LFULL) + t0 + (m & Tmask);
                    ((float*)Cp)[(size_t)gm * N + n] = v;
                } else {
                    ((__bf16*)Cp)[(size_t)m * N + n] = (__bf16)v;
                }
            }
        }
    }
}

// RMSNorm over D=1024, fp32 input read from token-slabbed global rows -> bf16 compact.
__global__ __launch_bounds__(256) void rmsnorm_f32in(
    const float* __restrict__ x, const float* __restrict__ g,
    __bf16* __restrict__ o, int sT, int t0)
{
    const int r = blockIdx.x;
    const int grow = ((r >> sT) * LFULL) + t0 + (r & ((1 << sT) - 1));
    const float* xr = x + (size_t)grow * 1024;
    const int tid = threadIdx.x;

    float4 v = *(const float4*)(xr + tid * 4);
    float vv[4] = {v.x, v.y, v.z, v.w};
    float ss = vv[0] * vv[0] + vv[1] * vv[1] + vv[2] * vv[2] + vv[3] * vv[3];
#pragma unroll
    for (int off = 32; off > 0; off >>= 1) ss += __shfl_down(ss, off);

    __shared__ float red[4];
    if ((tid & 63) == 0) red[tid >> 6] = ss;
    __syncthreads();
    const float tot = red[0] + red[1] + red[2] + red[3];
    const float scale = rsqrtf(tot * (1.0f / 1024.0f) + 1e-6f);

    float4 g4 = *(const float4*)(g + tid * 4);
    float gg[4] = {g4.x, g4.y, g4.z, g4.w};
    bf16x4 ov;
#pragma unroll
    for (int e = 0; e < 4; e++) ov[e] = (__bf16)(vv[e] * scale * gg[e]);
    *(bf16x4*)(o + (size_t)r * 1024 + tid * 4) = ov;
}

// RMSNorm over D=1024, bf16 compact input -> bf16 compact output.
__global__ __launch_bounds__(256) void rmsnorm_b16in(
    const __bf16* __restrict__ x, const float* __restrict__ g,
    __bf16* __restrict__ o)
{
    const int r = blockIdx.x;
    const __bf16* xr = x + (size_t)r * 1024;
    const int tid = threadIdx.x;

    bf16x4 v = *(const bf16x4*)(xr + tid * 4);
    float vv[4];
#pragma unroll
    for (int e = 0; e < 4; e++) vv[e] = (float)v[e];
    float ss = vv[0] * vv[0] + vv[1] * vv[1] + vv[2] * vv[2] + vv[3] * vv[3];
#pragma unroll
    for (int off = 32; off > 0; off >>= 1) ss += __shfl_down(ss, off);

    __shared__ float red[4];
    if ((tid & 63) == 0) red[tid >> 6] = ss;
    __syncthreads();
    const float tot = red[0] + red[1] + red[2] + red[3];
    const float scale = rsqrtf(tot * (1.0f / 1024.0f) + 1e-6f);

    float4 g4 = *(const float4*)(g + tid * 4);
    float gg[4] = {g4.x, g4.y, g4.z, g4.w};
    bf16x4 ov;
#pragma unroll
    for (int e = 0; e < 4; e++) ov[e] = (__bf16)(vv[e] * scale * gg[e]);
    *(bf16x4*)(o + (size_t)r * 1024 + tid * 4) = ov;
}

// Sequential recurrence over one token-chunk of T steps for all B*H=8192 channels.
// Gates in fp32 from bf16 pre-activations; carried state fp32 across chunks.
// Writes h (bf16) in place over zfio (each element read before overwrite).
__global__ __launch_bounds__(256) void scan_kernel(
    __bf16* zfio, const __bf16* __restrict__ zi,
    const float* __restrict__ hidden, float* __restrict__ state,
    float* __restrict__ hlast, int T, int first, int last)
{
    const int idx = blockIdx.x * 256 + threadIdx.x;   // 0..8191
    const int b = idx >> 11;
    const int h = idx & 2047;
    const float decay = (float)h * (1.0f / 2047.0f);
    float hp = first ? hidden[idx] : state[idx];
    const size_t base = ((size_t)b * T) * 2048 + h;
#pragma unroll 8
    for (int t = 0; t < T; t++) {
        const size_t p = base + (size_t)t * 2048;
        const float zfv = (float)zfio[p];
        const float ziv = (float)zi[p];
        const float r = decay / (1.f + __expf(-zfv));
        hp = (1.f - r) * hp + r * tanhf(ziv);
        zfio[p] = (__bf16)hp;
    }
    state[idx] = hp;
    if (last) hlast[idx] = hp;
}

// z1 *= silu(z2), bf16 compact, 8 elems/thread.
__global__ __launch_bounds__(256) void swiglu_kernel(
    __bf16* __restrict__ z1, const __bf16* __restrict__ z2)
{
    const size_t i0 = ((size_t)blockIdx.x * 256 + threadIdx.x) * 8;
    bf16x8 a = *(bf16x8*)(z1 + i0);
    bf16x8 bvec = *(const bf16x8*)(z2 + i0);
    bf16x8 o;
#pragma unroll
    for (int e = 0; e < 8; e++) {
        const float s = (float)bvec[e];
        const float sl = s / (1.f + __expf(-s));
        o[e] = (__bf16)((float)a[e] * sl);
    }
    *(bf16x8*)(z1 + i0) = o;
}

extern "C" void kernel_launch(void* const* d_in, const int* in_sizes, int n_in,
                              void* d_out, int out_size, void* d_ws, size_t ws_size,
                              hipStream_t stream)
{
    const float* x        = (const float*)d_in[0];
    const float* hidden   = (const float*)d_in[1];
    const float* w_forget = (const float*)d_in[2];
    const float* b_forget = (const float*)d_in[3];
    const float* w_input  = (const float*)d_in[4];
    const float* b_input  = (const float*)d_in[5];
    const float* w_hout   = (const float*)d_in[6];
    const float* b_hout   = (const float*)d_in[7];
    const float* w_fc     = (const float*)d_in[8];
    const float* b_fc     = (const float*)d_in[9];
    const float* w_fc_act = (const float*)d_in[10];
    const float* b_fc_act = (const float*)d_in[11];
    const float* w_fout   = (const float*)d_in[12];
    const float* b_fout   = (const float*)d_in[13];
    const float* g_norm1  = (const float*)d_in[14];
    const float* g_norm2  = (const float*)d_in[15];

    float* out   = (float*)d_out;
    float* hlast = out + (size_t)16384 * 1024;

    // Pick largest token-chunk T (per batch) whose workspace fits.
    // need(T) = Mc*(xn 2KB + zf 4KB + zi 4KB + x1 2KB rows) + state
    int T = 4096;
    while (T > 128) {
        size_t need = (size_t)4 * T * 12288 + 65536;
        if (need <= ws_size) break;
        T >>= 1;
    }
    const int NC = 4096 / T;
    int sT = 0; while ((1 << sT) < T) sT++;
    const int Mc = 4 * T;

    char* p = (char*)d_ws;
    __bf16* xn = (__bf16*)p; p += (size_t)Mc * 1024 * 2;
    __bf16* zf = (__bf16*)p; p += (size_t)Mc * 2048 * 2;
    __bf16* zi = (__bf16*)p; p += (size_t)Mc * 2048 * 2;
    __bf16* x1 = (__bf16*)p; p += (size_t)Mc * 1024 * 2;
    float* state = (float*)p;

    for (int c = 0; c < NC; c++) {
        const int t0 = c * T;
        // --- QGRU sub-block ---
        rmsnorm_f32in<<<Mc, 256, 0, stream>>>(x, g_norm1, xn, sT, t0);
        gemm_bt<0><<<dim3(16, Mc / 128), 256, 0, stream>>>(xn, w_forget, b_forget, nullptr, zf, 1024, 2048, sT, t0);
        gemm_bt<0><<<dim3(16, Mc / 128), 256, 0, stream>>>(xn, w_input,  b_input,  nullptr, zi, 1024, 2048, sT, t0);
        scan_kernel<<<32, 256, 0, stream>>>(zf, zi, hidden, state, hlast, T, (c == 0) ? 1 : 0, (c == NC - 1) ? 1 : 0);
        gemm_bt<1><<<dim3(8, Mc / 128), 256, 0, stream>>>(zf, w_hout, b_hout, x, x1, 2048, 1024, sT, t0);
        // --- FFN SwiGLU sub-block ---
        rmsnorm_b16in<<<Mc, 256, 0, stream>>>(x1, g_norm2, xn);
        gemm_bt<0><<<dim3(16, Mc / 128), 256, 0, stream>>>(xn, w_fc,     b_fc,     nullptr, zf, 1024, 2048, sT, t0);
        gemm_bt<0><<<dim3(16, Mc / 128), 256, 0, stream>>>(xn, w_fc_act, b_fc_act, nullptr, zi, 1024, 2048, sT, t0);
        swiglu_kernel<<<Mc, 256, 0, stream>>>(zf, zi);
        gemm_bt<2><<<dim3(8, Mc / 128), 256, 0, stream>>>(zf, w_fout, b_fout, x1, out, 2048, 1024, sT, t0);
    }
}

// Round 3
// 1191.926 us; speedup vs baseline: 2.1612x; 2.1612x over previous
//
#include <hip/hip_runtime.h>
#include <hip/hip_bf16.h>

typedef __bf16 bf16x8 __attribute__((ext_vector_type(8)));
typedef __bf16 bf16x4 __attribute__((ext_vector_type(4)));
typedef float floatx4 __attribute__((ext_vector_type(4)));

#define LFULL 4096

// async global->LDS, 16B per lane. LDS dest must be wave-uniform base + lane*16.
__device__ __forceinline__ void gll16(const __bf16* g, __bf16* l) {
    __builtin_amdgcn_global_load_lds(
        (const __attribute__((address_space(1))) void*)g,
        (__attribute__((address_space(3))) void*)l, 16, 0, 0);
}

// C[Mc,N] = A[Mc,K](bf16) @ B[N,K](bf16)^T + bias(fp32)
//   RD=0: C -> bf16 compact chunk buffer
//   RD=1: C -> bf16 compact, R = fp32 global (token-slabbed rows)
//   RD=2: C -> fp32 global (token-slabbed rows), R = bf16 compact
// Compact chunk row m maps to global row (m>>sT)*LFULL + t0 + (m&(T-1)).
template <int RD>
__global__ __launch_bounds__(256) void gemm_bt(
    const __bf16* __restrict__ A, const __bf16* __restrict__ Bw,
    const float* __restrict__ bias, const void* __restrict__ Rp,
    void* __restrict__ Cp, int K, int N, int sT, int t0)
{
    __shared__ __align__(16) __bf16 As[4][128][8];   // 8 KB: chunk c=(g*128+r) at byte c*16
    __shared__ __align__(16) __bf16 Bs[4][128][8];

    const int tid  = threadIdx.x;
    const int m0   = blockIdx.y * 128;
    const int n0   = blockIdx.x * 128;
    const int wave = tid >> 6;
    const int lane = tid & 63;
    const int wm   = (wave & 1) * 64;
    const int wn   = (wave >> 1) * 64;
    const int q    = lane >> 4;
    const int ml   = lane & 15;

    // staging: thread handles chunks c0=tid (g in {0,1}) and c0+256 (g in {2,3})
    const int r0 = tid & 127;
    const int g0 = tid >> 7;
    const __bf16* ga0 = A  + (size_t)(m0 + r0) * K + g0 * 8;
    const __bf16* gb0 = Bw + (size_t)(n0 + r0) * K + g0 * 8;
    __bf16* la0 = &As[g0][r0][0];
    __bf16* la1 = &As[g0 + 2][r0][0];
    __bf16* lb0 = &Bs[g0][r0][0];
    __bf16* lb1 = &Bs[g0 + 2][r0][0];

    floatx4 acc[4][4] = {};

    for (int k0 = 0; k0 < K; k0 += 32) {
        gll16(ga0, la0);
        gll16(ga0 + 16, la1);
        gll16(gb0, lb0);
        gll16(gb0 + 16, lb1);
        ga0 += 32; gb0 += 32;
        __syncthreads();   // drains vmcnt (global_load_lds) before LDS reads

        bf16x8 af[4], bfr[4];
#pragma unroll
        for (int i = 0; i < 4; i++) {
            af[i]  = *(const bf16x8*)&As[q][wm + i * 16 + ml][0];
            bfr[i] = *(const bf16x8*)&Bs[q][wn + i * 16 + ml][0];
        }
#pragma unroll
        for (int i = 0; i < 4; i++)
#pragma unroll
            for (int j = 0; j < 4; j++)
                acc[i][j] = __builtin_amdgcn_mfma_f32_16x16x32_bf16(af[i], bfr[j], acc[i][j], 0, 0, 0);
        __syncthreads();
    }

    const int Tmask = (1 << sT) - 1;
#pragma unroll
    for (int i = 0; i < 4; i++) {
#pragma unroll
        for (int j = 0; j < 4; j++) {
            const int n = n0 + wn + j * 16 + ml;
            const float bv = bias[n];
#pragma unroll
            for (int r = 0; r < 4; r++) {
                const int m = m0 + wm + i * 16 + q * 4 + r;
                float v = acc[i][j][r] + bv;
                if (RD == 1) {
                    const int gm = ((m >> sT) * LFULL) + t0 + (m & Tmask);
                    v += ((const float*)Rp)[(size_t)gm * N + n];
                    ((__bf16*)Cp)[(size_t)m * N + n] = (__bf16)v;
                } else if (RD == 2) {
                    v += (float)((const __bf16*)Rp)[(size_t)m * N + n];
                    const int gm = ((m >> sT) * LFULL) + t0 + (m & Tmask);
                    ((float*)Cp)[(size_t)gm * N + n] = v;
                } else {
                    ((__bf16*)Cp)[(size_t)m * N + n] = (__bf16)v;
                }
            }
        }
    }
}

// fp32 -> bf16 weight conversion; blockIdx.y selects one of 6 weights (2M elems each).
__global__ __launch_bounds__(256) void cvt_w(
    const float* __restrict__ s0, const float* __restrict__ s1,
    const float* __restrict__ s2, const float* __restrict__ s3,
    const float* __restrict__ s4, const float* __restrict__ s5,
    __bf16* __restrict__ dst)
{
    const float* srcs[6] = {s0, s1, s2, s3, s4, s5};
    const float* s = srcs[blockIdx.y];
    __bf16* d = dst + (size_t)blockIdx.y * 2097152;
    const int i = (blockIdx.x * 256 + threadIdx.x) * 8;
    float4 f0 = *(const float4*)(s + i);
    float4 f1 = *(const float4*)(s + i + 4);
    bf16x8 o;
    o[0] = (__bf16)f0.x; o[1] = (__bf16)f0.y; o[2] = (__bf16)f0.z; o[3] = (__bf16)f0.w;
    o[4] = (__bf16)f1.x; o[5] = (__bf16)f1.y; o[6] = (__bf16)f1.z; o[7] = (__bf16)f1.w;
    *(bf16x8*)(d + i) = o;
}

// RMSNorm over D=1024, fp32 token-slabbed input -> bf16 compact.
__global__ __launch_bounds__(256) void rmsnorm_f32in(
    const float* __restrict__ x, const float* __restrict__ g,
    __bf16* __restrict__ o, int sT, int t0)
{
    const int r = blockIdx.x;
    const int grow = ((r >> sT) * LFULL) + t0 + (r & ((1 << sT) - 1));
    const float* xr = x + (size_t)grow * 1024;
    const int tid = threadIdx.x;

    float4 v = *(const float4*)(xr + tid * 4);
    float vv[4] = {v.x, v.y, v.z, v.w};
    float ss = vv[0] * vv[0] + vv[1] * vv[1] + vv[2] * vv[2] + vv[3] * vv[3];
#pragma unroll
    for (int off = 32; off > 0; off >>= 1) ss += __shfl_down(ss, off);

    __shared__ float red[4];
    if ((tid & 63) == 0) red[tid >> 6] = ss;
    __syncthreads();
    const float tot = red[0] + red[1] + red[2] + red[3];
    const float scale = rsqrtf(tot * (1.0f / 1024.0f) + 1e-6f);

    float4 g4 = *(const float4*)(g + tid * 4);
    float gg[4] = {g4.x, g4.y, g4.z, g4.w};
    bf16x4 ov;
#pragma unroll
    for (int e = 0; e < 4; e++) ov[e] = (__bf16)(vv[e] * scale * gg[e]);
    *(bf16x4*)(o + (size_t)r * 1024 + tid * 4) = ov;
}

// RMSNorm over D=1024, bf16 compact -> bf16 compact.
__global__ __launch_bounds__(256) void rmsnorm_b16in(
    const __bf16* __restrict__ x, const float* __restrict__ g,
    __bf16* __restrict__ o)
{
    const int r = blockIdx.x;
    const __bf16* xr = x + (size_t)r * 1024;
    const int tid = threadIdx.x;

    bf16x4 v = *(const bf16x4*)(xr + tid * 4);
    float vv[4];
#pragma unroll
    for (int e = 0; e < 4; e++) vv[e] = (float)v[e];
    float ss = vv[0] * vv[0] + vv[1] * vv[1] + vv[2] * vv[2] + vv[3] * vv[3];
#pragma unroll
    for (int off = 32; off > 0; off >>= 1) ss += __shfl_down(ss, off);

    __shared__ float red[4];
    if ((tid & 63) == 0) red[tid >> 6] = ss;
    __syncthreads();
    const float tot = red[0] + red[1] + red[2] + red[3];
    const float scale = rsqrtf(tot * (1.0f / 1024.0f) + 1e-6f);

    float4 g4 = *(const float4*)(g + tid * 4);
    float gg[4] = {g4.x, g4.y, g4.z, g4.w};
    bf16x4 ov;
#pragma unroll
    for (int e = 0; e < 4; e++) ov[e] = (__bf16)(vv[e] * scale * gg[e]);
    *(bf16x4*)(o + (size_t)r * 1024 + tid * 4) = ov;
}

// ---- parallel linear-recurrence scan: h[t] = (1-r)h[t-1] + r*tanh(zi) ----
// Pass 1: 32-step sub-chunk summaries (A = prod a, B = scan from 0), fp32.
__global__ __launch_bounds__(256) void scan_pass1(
    const __bf16* __restrict__ zf, const __bf16* __restrict__ zi,
    float* __restrict__ Ach, float* __restrict__ Bch, int T)
{
    const int h = blockIdx.x * 256 + threadIdx.x;  // 0..2047
    const int s = blockIdx.y;                      // sub-chunk
    const int b = blockIdx.z;
    const int NSC = T >> 5;
    const float decay = (float)h * (1.0f / 2047.0f);
    size_t p = ((size_t)b * T + s * 32) * 2048 + h;
    float Aa = 1.f, Bv = 0.f;
#pragma unroll 8
    for (int t = 0; t < 32; t++, p += 2048) {
        const float r = decay / (1.f + __expf(-(float)zf[p]));
        const float e = __expf(2.f * (float)zi[p]);
        const float th = 1.f - 2.f / (e + 1.f);     // tanh, saturates safely at +-1
        const float a = 1.f - r;
        Aa *= a;
        Bv = a * Bv + r * th;
    }
    const size_t qq = (size_t)(b * NSC + s) * 2048 + h;
    Ach[qq] = Aa; Bch[qq] = Bv;
}

// Pass 2: sequential composition over sub-chunk summaries; emits start-state per sub-chunk.
__global__ __launch_bounds__(256) void scan_pass2(
    const float* __restrict__ Ach, const float* __restrict__ Bch,
    float* __restrict__ hst, const float* __restrict__ hidden,
    float* __restrict__ state, float* __restrict__ hlast,
    int NSC, int first, int last)
{
    const int idx = blockIdx.x * 256 + threadIdx.x;  // 0..8191 = (b,h)
    const int b = idx >> 11;
    const int h = idx & 2047;
    float hs = first ? hidden[idx] : state[idx];
    size_t qq = (size_t)b * NSC * 2048 + h;
#pragma unroll 4
    for (int s = 0; s < NSC; s++, qq += 2048) {
        hst[qq] = hs;
        hs = Ach[qq] * hs + Bch[qq];
    }
    state[idx] = hs;
    if (last) hlast[idx] = hs;
}

// Pass 3: replay each sub-chunk from its fp32 start state; write h (bf16) over zf in place.
__global__ __launch_bounds__(256) void scan_pass3(
    __bf16* __restrict__ zfio, const __bf16* __restrict__ zi,
    const float* __restrict__ hst, int T)
{
    const int h = blockIdx.x * 256 + threadIdx.x;
    const int s = blockIdx.y;
    const int b = blockIdx.z;
    const int NSC = T >> 5;
    const float decay = (float)h * (1.0f / 2047.0f);
    float hp = hst[(size_t)(b * NSC + s) * 2048 + h];
    size_t p = ((size_t)b * T + s * 32) * 2048 + h;
#pragma unroll 8
    for (int t = 0; t < 32; t++, p += 2048) {
        const float r = decay / (1.f + __expf(-(float)zfio[p]));
        const float e = __expf(2.f * (float)zi[p]);
        const float th = 1.f - 2.f / (e + 1.f);
        hp = (1.f - r) * hp + r * th;
        zfio[p] = (__bf16)hp;
    }
}

// z1 *= silu(z2), bf16 compact, 8 elems/thread.
__global__ __launch_bounds__(256) void swiglu_kernel(
    __bf16* __restrict__ z1, const __bf16* __restrict__ z2)
{
    const size_t i0 = ((size_t)blockIdx.x * 256 + threadIdx.x) * 8;
    bf16x8 a = *(bf16x8*)(z1 + i0);
    bf16x8 bvec = *(const bf16x8*)(z2 + i0);
    bf16x8 o;
#pragma unroll
    for (int e = 0; e < 8; e++) {
        const float s = (float)bvec[e];
        const float sl = s / (1.f + __expf(-s));
        o[e] = (__bf16)((float)a[e] * sl);
    }
    *(bf16x8*)(z1 + i0) = o;
}

extern "C" void kernel_launch(void* const* d_in, const int* in_sizes, int n_in,
                              void* d_out, int out_size, void* d_ws, size_t ws_size,
                              hipStream_t stream)
{
    const float* x        = (const float*)d_in[0];
    const float* hidden   = (const float*)d_in[1];
    const float* w_forget = (const float*)d_in[2];
    const float* b_forget = (const float*)d_in[3];
    const float* w_input  = (const float*)d_in[4];
    const float* b_input  = (const float*)d_in[5];
    const float* w_hout   = (const float*)d_in[6];
    const float* b_hout   = (const float*)d_in[7];
    const float* w_fc     = (const float*)d_in[8];
    const float* b_fc     = (const float*)d_in[9];
    const float* w_fc_act = (const float*)d_in[10];
    const float* b_fc_act = (const float*)d_in[11];
    const float* w_fout   = (const float*)d_in[12];
    const float* b_fout   = (const float*)d_in[13];
    const float* g_norm1  = (const float*)d_in[14];
    const float* g_norm2  = (const float*)d_in[15];

    float* out   = (float*)d_out;
    float* hlast = out + (size_t)16384 * 1024;

    // workspace need(T): wb 24MB + chunk activations + scan summaries + state
    int T = 4096;
    for (;;) {
        size_t need = 25165824ull + (size_t)4 * T * 12288 + 3ull * 4 * (T / 32) * 2048 * 4 + 65536;
        if (need <= ws_size || T == 256) break;
        T >>= 1;
    }
    const int NC = 4096 / T;
    int sT = 0; while ((1 << sT) < T) sT++;
    const int Mc = 4 * T;
    const int NSC = T >> 5;

    char* p = (char*)d_ws;
    __bf16* wb = (__bf16*)p; p += 25165824ull;          // 6 weights bf16, 2M elems each
    __bf16* xn = (__bf16*)p; p += (size_t)Mc * 1024 * 2;
    __bf16* zf = (__bf16*)p; p += (size_t)Mc * 2048 * 2;
    __bf16* zi = (__bf16*)p; p += (size_t)Mc * 2048 * 2;
    __bf16* x1 = (__bf16*)p; p += (size_t)Mc * 1024 * 2;
    float* Ach = (float*)p;  p += (size_t)4 * NSC * 2048 * 4;
    float* Bch = (float*)p;  p += (size_t)4 * NSC * 2048 * 4;
    float* hst = (float*)p;  p += (size_t)4 * NSC * 2048 * 4;
    float* state = (float*)p;

    __bf16* wb_f  = wb;
    __bf16* wb_i  = wb + 2097152;
    __bf16* wb_fc = wb + 2 * 2097152;
    __bf16* wb_fa = wb + 3 * 2097152;
    __bf16* wb_h  = wb + 4 * 2097152;
    __bf16* wb_o  = wb + 5 * 2097152;

    cvt_w<<<dim3(1024, 6), 256, 0, stream>>>(w_forget, w_input, w_fc, w_fc_act, w_hout, w_fout, wb);

    for (int c = 0; c < NC; c++) {
        const int t0 = c * T;
        // --- QGRU sub-block ---
        rmsnorm_f32in<<<Mc, 256, 0, stream>>>(x, g_norm1, xn, sT, t0);
        gemm_bt<0><<<dim3(16, Mc / 128), 256, 0, stream>>>(xn, wb_f, b_forget, nullptr, zf, 1024, 2048, sT, t0);
        gemm_bt<0><<<dim3(16, Mc / 128), 256, 0, stream>>>(xn, wb_i, b_input,  nullptr, zi, 1024, 2048, sT, t0);
        scan_pass1<<<dim3(8, NSC, 4), 256, 0, stream>>>(zf, zi, Ach, Bch, T);
        scan_pass2<<<32, 256, 0, stream>>>(Ach, Bch, hst, hidden, state, hlast, NSC,
                                           (c == 0) ? 1 : 0, (c == NC - 1) ? 1 : 0);
        scan_pass3<<<dim3(8, NSC, 4), 256, 0, stream>>>(zf, zi, hst, T);
        gemm_bt<1><<<dim3(8, Mc / 128), 256, 0, stream>>>(zf, wb_h, b_hout, x, x1, 2048, 1024, sT, t0);
        // --- FFN SwiGLU sub-block ---
        rmsnorm_b16in<<<Mc, 256, 0, stream>>>(x1, g_norm2, xn);
        gemm_bt<0><<<dim3(16, Mc / 128), 256, 0, stream>>>(xn, wb_fc, b_fc,     nullptr, zf, 1024, 2048, sT, t0);
        gemm_bt<0><<<dim3(16, Mc / 128), 256, 0, stream>>>(xn, wb_fa, b_fc_act, nullptr, zi, 1024, 2048, sT, t0);
        swiglu_kernel<<<Mc, 256, 0, stream>>>(zf, zi);
        gemm_bt<2><<<dim3(8, Mc / 128), 256, 0, stream>>>(zf, wb_o, b_fout, x1, out, 2048, 1024, sT, t0);
    }
}